// Round 4
// baseline (30.971 us; speedup 1.0000x reference)
//
#include <hip/hip_runtime.h>

#define BB 128
#define CC 3
#define HH 224
#define WW 224
#define KK 1000

#define WV (WW / 4)              // 56 vec4 per row
#define PLANE (HH * WV)          // 12544 vec4 per (b,c) plane
#define PER_B (CC * PLANE)       // 37632 vec4 per sample = 147 blocks * 256
#define IMG_BLOCKS (PER_B / 256) // 147
#define KV (KK / 4)              // 250 label vec4 per sample

typedef float v4f __attribute__((ext_vector_type(4)));

__global__ __launch_bounds__(256) void cutmix_fused_kernel(
        const float* __restrict__ img,
        const float* __restrict__ lab,
        const int* __restrict__ perm,
        const int* __restrict__ box,
        const int* __restrict__ xs,
        const int* __restrict__ ys,
        const int* __restrict__ keep,
        float* __restrict__ out_img,
        float* __restrict__ out_lab) {
    const int b = blockIdx.y;          // scalar: all per-sample params -> s_load
    const int kp = keep[b];
    const int x0 = xs[b];
    const int bs = box[b];
    const int y0 = ys[b];
    const int pb = perm[b];

    if (blockIdx.x < IMG_BLOCKS) {
        // ---- image path: one thread per float4 ----
        int idx = blockIdx.x * 256 + threadIdx.x;   // [0, 37632)
        int c  = idx / PLANE;
        int r  = idx - c * PLANE;
        int h  = r / WV;
        int wv = r - h * WV;
        int w0 = wv * 4;

        size_t base = (((size_t)(b * CC + c) * HH) + h) * WW + w0;
        v4f v;
        bool row_in = kp && ((unsigned)(h - x0) < (unsigned)bs);
        if (row_in) {
            int y1 = y0 + bs;
            bool full = (w0 >= y0) && (w0 + 4 <= y1);
            size_t sbase = (((size_t)(pb * CC + c) * HH) + h) * WW + w0;
            v = *reinterpret_cast<const v4f*>(img + (full ? sbase : base));
            if (!full && (w0 + 4 > y0) && (w0 < y1)) {
                // edge vec4 (at most 2 per row): blend per lane
                v4f s = *reinterpret_cast<const v4f*>(img + sbase);
#pragma unroll
                for (int j = 0; j < 4; ++j) {
                    int w = w0 + j;
                    if (w >= y0 && w < y1) v[j] = s[j];
                }
            }
        } else {
            v = *reinterpret_cast<const v4f*>(img + base);
        }
        __builtin_nontemporal_store(v, reinterpret_cast<v4f*>(out_img + base));
    } else {
        // ---- label path: block x == IMG_BLOCKS, 250 active threads ----
        int kv = threadIdx.x;
        if (kv >= KV) return;
        size_t base = (size_t)b * KK + kv * 4;
        v4f l = *reinterpret_cast<const v4f*>(lab + base);
        v4f o = l;
        if (kp) {
            float bsf = (float)bs;
            float lam = 1.0f - bsf * bsf / (float)(HH * WW);
            float om = 1.0f - lam;
            v4f s = *reinterpret_cast<const v4f*>(lab + (size_t)pb * KK + kv * 4);
            o = lam * l + om * s;
        }
        __builtin_nontemporal_store(o, reinterpret_cast<v4f*>(out_lab + base));
    }
}

extern "C" void kernel_launch(void* const* d_in, const int* in_sizes, int n_in,
                              void* d_out, int out_size, void* d_ws, size_t ws_size,
                              hipStream_t stream) {
    const float* images = (const float*)d_in[0];
    const float* labels = (const float*)d_in[1];
    const int* perm     = (const int*)d_in[2];
    const int* box      = (const int*)d_in[3];
    const int* xs       = (const int*)d_in[4];
    const int* ys       = (const int*)d_in[5];
    const int* keep     = (const int*)d_in[6];

    float* out_imgs = (float*)d_out;                                  // B*C*H*W floats
    float* out_labs = (float*)d_out + (size_t)BB * CC * HH * WW;      // B*K floats

    dim3 grid(IMG_BLOCKS + 1, BB);   // (148, 128)
    cutmix_fused_kernel<<<grid, 256, 0, stream>>>(
        images, labels, perm, box, xs, ys, keep, out_imgs, out_labs);
}

// Round 6
// 30.337 us; speedup vs baseline: 1.0209x; 1.0209x over previous
//
#include <hip/hip_runtime.h>

#define BB 128
#define CC 3
#define HH 224
#define WW 224
#define KK 1000

#define WV (WW / 4)              // 56 vec4 per row
#define PLANE (HH * WV)          // 12544 vec4 per (b,c) plane
#define PER_B (CC * PLANE)       // 37632 vec4 per sample
#define VPT 4                    // vec4 per thread
#define IMG_BLOCKS ((PER_B + 256 * VPT - 1) / (256 * VPT))  // 37 (last has 3 valid j)
#define KV (KK / 4)              // 250 label vec4 per sample

typedef float v4f __attribute__((ext_vector_type(4)));

__global__ __launch_bounds__(256) void cutmix_fused_kernel(
        const float* __restrict__ img,
        const float* __restrict__ lab,
        const int* __restrict__ perm,
        const int* __restrict__ box,
        const int* __restrict__ xs,
        const int* __restrict__ ys,
        const int* __restrict__ keep,
        float* __restrict__ out_img,
        float* __restrict__ out_lab) {
    const int b = blockIdx.y;          // scalar: per-sample params -> s_load
    const int kp = keep[b];
    const int x0 = xs[b];
    const int bs = box[b];
    const int y0 = ys[b];
    const int pb = perm[b];

    if (blockIdx.x < IMG_BLOCKS) {
        // ---- image path: VPT float4 per thread, coalesced 256-chunks ----
        const int y1 = y0 + bs;
        v4f v[VPT];
        size_t base[VPT];
        bool valid[VPT];

#pragma unroll
        for (int j = 0; j < VPT; ++j) {
            int idx = blockIdx.x * (256 * VPT) + j * 256 + threadIdx.x;
            valid[j] = idx < PER_B;          // uniform per (block,j)
            if (valid[j]) {
                int c  = idx / PLANE;
                int r  = idx - c * PLANE;
                int h  = r / WV;
                int wv = r - h * WV;
                int w0 = wv * 4;

                size_t ba = (((size_t)(b * CC + c) * HH) + h) * WW + w0;
                base[j] = ba;
                bool row_in = kp && ((unsigned)(h - x0) < (unsigned)bs);
                bool full = false, eg = false;
                size_t sbase = 0;
                if (row_in) {
                    full = (w0 >= y0) && (w0 + 4 <= y1);
                    bool any = (w0 + 4 > y0) && (w0 < y1);
                    eg = any && !full;
                    sbase = (((size_t)(pb * CC + c) * HH) + h) * WW + w0;
                }
                // primary load: permuted source iff fully inside box
                v[j] = *reinterpret_cast<const v4f*>(img + (full ? sbase : ba));
                if (eg) {
                    // edge vec4 (rare): blend per lane now
                    v4f s = *reinterpret_cast<const v4f*>(img + sbase);
#pragma unroll
                    for (int q = 0; q < 4; ++q) {
                        int w = w0 + q;
                        if (w >= y0 && w < y1) v[j][q] = s[q];
                    }
                }
            }
        }
#pragma unroll
        for (int j = 0; j < VPT; ++j) {
            if (valid[j]) {
                *reinterpret_cast<v4f*>(out_img + base[j]) = v[j];
            }
        }
    } else {
        // ---- label path: block x == IMG_BLOCKS, 250 active threads ----
        int kv = threadIdx.x;
        if (kv >= KV) return;
        size_t base = (size_t)b * KK + kv * 4;
        v4f l = *reinterpret_cast<const v4f*>(lab + base);
        v4f o = l;
        if (kp) {
            float bsf = (float)bs;
            float lam = 1.0f - bsf * bsf / (float)(HH * WW);
            float om = 1.0f - lam;
            v4f s = *reinterpret_cast<const v4f*>(lab + (size_t)pb * KK + kv * 4);
            o = lam * l + om * s;
        }
        *reinterpret_cast<v4f*>(out_lab + base) = o;
    }
}

extern "C" void kernel_launch(void* const* d_in, const int* in_sizes, int n_in,
                              void* d_out, int out_size, void* d_ws, size_t ws_size,
                              hipStream_t stream) {
    const float* images = (const float*)d_in[0];
    const float* labels = (const float*)d_in[1];
    const int* perm     = (const int*)d_in[2];
    const int* box      = (const int*)d_in[3];
    const int* xs       = (const int*)d_in[4];
    const int* ys       = (const int*)d_in[5];
    const int* keep     = (const int*)d_in[6];

    float* out_imgs = (float*)d_out;                                  // B*C*H*W floats
    float* out_labs = (float*)d_out + (size_t)BB * CC * HH * WW;      // B*K floats

    dim3 grid(IMG_BLOCKS + 1, BB);   // (38, 128)
    cutmix_fused_kernel<<<grid, 256, 0, stream>>>(
        images, labels, perm, box, xs, ys, keep, out_imgs, out_labs);
}